// Round 7
// baseline (762.354 us; speedup 1.0000x reference)
//
#include <hip/hip_runtime.h>
#include <hip/hip_bf16.h>

typedef __hip_bfloat16 bf16;
typedef __attribute__((ext_vector_type(8))) short bf16x8;
typedef __attribute__((ext_vector_type(4))) short bf16x4v;
typedef __attribute__((ext_vector_type(4))) float f32x4;

__device__ __forceinline__ void gload_lds16(const void* g, void* l)
{
    __builtin_amdgcn_global_load_lds(
        (const __attribute__((address_space(1))) void*)g,
        (__attribute__((address_space(3))) void*)l, 16, 0, 0);
}

// ---------------------------------------------------------------------------
// MFMA bf16 GEMM: C = epi(A @ Bt^T + bias)  (same as round 6)
// ---------------------------------------------------------------------------
template<typename TA, typename TC, int EPI>
__global__ __launch_bounds__(256) void mgemm(
    const TA* __restrict__ A, const bf16* __restrict__ Bt,
    const float* __restrict__ bias, const float* __restrict__ rowscale,
    TC* __restrict__ C, int M, int K, int N, int ka,
    const int* __restrict__ Aperm)
{
    __shared__ __align__(16) bf16 As[128 * 32];
    __shared__ __align__(16) bf16 Bs[128 * 32];
    const int tid = threadIdx.x;
    const int lane = tid & 63;
    const int wave = tid >> 6;
    const int col16 = lane & 15;
    const int quad = lane >> 4;
    const int wm = (wave & 1) * 64;
    const int wn = (wave >> 1) * 64;
    const size_t m0 = (size_t)blockIdx.x * 128;
    const int n0 = blockIdx.y * 128;

    f32x4 acc[4][4];
#pragma unroll
    for (int i = 0; i < 4; ++i)
#pragma unroll
        for (int j = 0; j < 4; ++j) acc[i][j] = (f32x4){0.f, 0.f, 0.f, 0.f};

    const int rbase = wave * 32;
    const int srow = lane >> 2;
    const int schk = lane & 3;

    for (int k0 = 0; k0 < K; k0 += 32) {
        if constexpr (sizeof(TA) == 2) {
            const bf16* g0 = (const bf16*)A + (m0 + rbase + srow) * (size_t)K + k0 + schk * 8;
            gload_lds16(g0, As + rbase * 32);
            gload_lds16(g0 + 16 * (size_t)K, As + (rbase + 16) * 32);
        } else {
#pragma unroll
            for (int r = 0; r < 4; ++r) {
                int p = tid + 256 * r;
                int row = p >> 3, kp = p & 7;
                int kg = k0 + kp * 4;
                size_t arow = Aperm ? (size_t)Aperm[m0 + row] : (m0 + row);
                float4 v = make_float4(0.f, 0.f, 0.f, 0.f);
                if (kg < ka) v = *(const float4*)((const float*)A + arow * (size_t)ka + kg);
                bf16 t[4] = {__float2bfloat16(v.x), __float2bfloat16(v.y),
                             __float2bfloat16(v.z), __float2bfloat16(v.w)};
                *(bf16x4v*)(As + row * 32 + kp * 4) = *(const bf16x4v*)t;
            }
        }
        {
            const bf16* g0 = Bt + (size_t)(n0 + rbase + srow) * K + k0 + schk * 8;
            gload_lds16(g0, Bs + rbase * 32);
            gload_lds16(g0 + 16 * (size_t)K, Bs + (rbase + 16) * 32);
        }
        __syncthreads();

        bf16x8 a[4], b[4];
#pragma unroll
        for (int i = 0; i < 4; ++i)
            a[i] = *(const bf16x8*)(As + (wm + i * 16 + col16) * 32 + quad * 8);
#pragma unroll
        for (int j = 0; j < 4; ++j)
            b[j] = *(const bf16x8*)(Bs + (wn + j * 16 + col16) * 32 + quad * 8);
#pragma unroll
        for (int i = 0; i < 4; ++i)
#pragma unroll
            for (int j = 0; j < 4; ++j)
                acc[i][j] = __builtin_amdgcn_mfma_f32_16x16x32_bf16(a[i], b[j], acc[i][j], 0, 0, 0);
        __syncthreads();
    }

#pragma unroll
    for (int j = 0; j < 4; ++j) {
        int col = n0 + wn + j * 16 + col16;
        float bv = bias ? bias[col] : 0.f;
#pragma unroll
        for (int i = 0; i < 4; ++i) {
#pragma unroll
            for (int r = 0; r < 4; ++r) {
                size_t row = m0 + wm + i * 16 + quad * 4 + r;
                float v = acc[i][j][r] + bv;
                if (EPI == 1) v = v / (1.f + expf(-v));
                if (EPI == 2) v *= rowscale[row];
                if constexpr (sizeof(TC) == 2)
                    ((bf16*)C)[row * (size_t)N + col] = __float2bfloat16(v);
                else
                    ((float*)C)[row * (size_t)N + col] = v;
            }
        }
    }
}

// Fused weight transpose+convert for all 7 weights.
struct CvtArgs {
    const float* in[7];
    bf16* out[7];
    int K[7], Nc[7], Kp[7];
    int cum[8];
};
__global__ __launch_bounds__(256) void cvt_all(CvtArgs a)
{
    int i = blockIdx.x * 256 + threadIdx.x;
#pragma unroll
    for (int s = 0; s < 7; ++s) {
        if (i >= a.cum[s] && i < a.cum[s + 1]) {
            int j = i - a.cum[s];
            int n = j / a.Kp[s], k = j - n * a.Kp[s];
            a.out[s][j] = __float2bfloat16(
                k < a.K[s] ? a.in[s][(size_t)k * a.Nc[s] + n] : 0.f);
        }
    }
}

__global__ __launch_bounds__(256) void cvt_bf16(
    const float4* __restrict__ in, bf16* __restrict__ out, size_t n4)
{
    size_t i = (size_t)blockIdx.x * 256 + threadIdx.x;
    if (i >= n4) return;
    float4 v = in[i];
    bf16 t[4] = {__float2bfloat16(v.x), __float2bfloat16(v.y),
                 __float2bfloat16(v.z), __float2bfloat16(v.w)};
    *(bf16x4v*)(out + i * 4) = *(const bf16x4v*)t;
}

__global__ __launch_bounds__(256) void zero_k(float4* __restrict__ p, size_t n4)
{
    size_t i = (size_t)blockIdx.x * 256 + threadIdx.x;
    if (i < n4) p[i] = make_float4(0.f, 0.f, 0.f, 0.f);
}

// ---- counting sort by target ----
__global__ __launch_bounds__(256) void hist_k(
    const int* __restrict__ ei, int* __restrict__ hist, int E)
{
    int e = blockIdx.x * 256 + threadIdx.x;
    if (e < E) atomicAdd(&hist[ei[e]], 1);
}

// Single block, 256 threads, 128 targets each. 8 groups of 4096 targets
// (32 threads per group); group g's region starts at g*SLOT.
__global__ __launch_bounds__(256) void scan_k(
    const int* __restrict__ hist, int* __restrict__ off,
    int* __restrict__ cursor, int N, int SLOT)
{
    __shared__ int ps[256];
    int tid = threadIdx.x;
    int base = tid * 128;
    int s = 0;
    for (int i = 0; i < 128; ++i) s += hist[base + i];
    ps[tid] = s;
    __syncthreads();
    if (tid == 0) {
        int run = 0;
        for (int t = 0; t < 256; ++t) {
            if ((t & 31) == 0) run = 0;       // new group
            int tmp = ps[t]; ps[t] = run; run += tmp;
        }
    }
    __syncthreads();
    int g = tid >> 5;
    int run = g * SLOT + ps[tid];
    for (int i = 0; i < 128; ++i) {
        int n = base + i;
        off[n] = run; cursor[n] = run;
        run += hist[n];
    }
}

__global__ __launch_bounds__(256) void scatter_k(
    const int* __restrict__ ei, const float* __restrict__ uv,
    const float* __restrict__ cut, int* __restrict__ cursor,
    int* __restrict__ perm, int* __restrict__ srcp,
    float* __restrict__ cutp, float* __restrict__ uvp, int E)
{
    int e = blockIdx.x * 256 + threadIdx.x;
    if (e >= E) return;
    int tgt = ei[e];
    int pos = atomicAdd(&cursor[tgt], 1);
    perm[pos] = e;
    srcp[pos] = ei[E + e];
    cutp[pos] = cut[e];
    uvp[pos * 3 + 0] = uv[e * 3 + 0];
    uvp[pos * 3 + 1] = uv[e * 3 + 1];
    uvp[pos * 3 + 2] = uv[e * 3 + 2];
}

// ---- segmented edge reduction: one wave per target, unrolled x2 ----
// Segment length from hist (off[n+1] would cross region slack).
__global__ __launch_bounds__(256) void edge_seg(
    const bf16* __restrict__ x, const bf16* __restrict__ filt,
    const bf16* __restrict__ mub, const int* __restrict__ srcp,
    const float* __restrict__ uvp, const int* __restrict__ off,
    const int* __restrict__ hist,
    const float* __restrict__ q, const float* __restrict__ mu,
    float* __restrict__ outq, float* __restrict__ outmu,
    int t0, int tcount, int base)
{
    int t = blockIdx.x * 4 + (threadIdx.x >> 6);
    if (t >= tcount) return;
    int n = t0 + t;
    int lane = threadIdx.x & 63;
    int h = lane * 2;
    int p0 = off[n];
    int cnt = hist[n];
    int p1 = p0 + cnt;

    float aq0 = 0.f, aq1 = 0.f;
    float am00 = 0.f, am01 = 0.f, am10 = 0.f, am11 = 0.f, am20 = 0.f, am21 = 0.f;

#define EDGE_LOAD(P, S) \
    const bf16* fp##S = filt + (size_t)((P) - base) * 384; \
    int src##S = srcp[P]; \
    const bf16* xp##S = x + (size_t)src##S * 384; \
    const bf16* mp##S = mub + (size_t)src##S * 384; \
    __hip_bfloat162 fq##S = *(const __hip_bfloat162*)(fp##S + h); \
    __hip_bfloat162 fr##S = *(const __hip_bfloat162*)(fp##S + 128 + h); \
    __hip_bfloat162 fm##S = *(const __hip_bfloat162*)(fp##S + 256 + h); \
    __hip_bfloat162 xq##S = *(const __hip_bfloat162*)(xp##S + h); \
    __hip_bfloat162 xr##S = *(const __hip_bfloat162*)(xp##S + 128 + h); \
    __hip_bfloat162 xm##S = *(const __hip_bfloat162*)(xp##S + 256 + h); \
    __hip_bfloat162 m0##S = *(const __hip_bfloat162*)(mp##S + h); \
    __hip_bfloat162 m1##S = *(const __hip_bfloat162*)(mp##S + 128 + h); \
    __hip_bfloat162 m2##S = *(const __hip_bfloat162*)(mp##S + 256 + h); \
    float u0##S = uvp[(P) * 3 + 0]; \
    float u1##S = uvp[(P) * 3 + 1]; \
    float u2##S = uvp[(P) * 3 + 2];

#define EDGE_ACC(S) { \
    float xq0_ = __bfloat162float(xq##S.x) * __bfloat162float(fq##S.x); \
    float xq1_ = __bfloat162float(xq##S.y) * __bfloat162float(fq##S.y); \
    float xr0_ = __bfloat162float(xr##S.x) * __bfloat162float(fr##S.x); \
    float xr1_ = __bfloat162float(xr##S.y) * __bfloat162float(fr##S.y); \
    float xm0_ = __bfloat162float(xm##S.x) * __bfloat162float(fm##S.x); \
    float xm1_ = __bfloat162float(xm##S.y) * __bfloat162float(fm##S.y); \
    aq0 += xq0_; aq1 += xq1_; \
    am00 += fmaf(u0##S, xr0_, __bfloat162float(m0##S.x) * xm0_); \
    am01 += fmaf(u0##S, xr1_, __bfloat162float(m0##S.y) * xm1_); \
    am10 += fmaf(u1##S, xr0_, __bfloat162float(m1##S.x) * xm0_); \
    am11 += fmaf(u1##S, xr1_, __bfloat162float(m1##S.y) * xm1_); \
    am20 += fmaf(u2##S, xr0_, __bfloat162float(m2##S.x) * xm0_); \
    am21 += fmaf(u2##S, xr1_, __bfloat162float(m2##S.y) * xm1_); }

    int p = p0;
    for (; p + 2 <= p1; p += 2) {
        EDGE_LOAD(p, A)
        EDGE_LOAD(p + 1, B)
        EDGE_ACC(A)
        EDGE_ACC(B)
    }
    if (p < p1) {
        EDGE_LOAD(p, A)
        EDGE_ACC(A)
    }
#undef EDGE_LOAD
#undef EDGE_ACC

    float inv = 1.f / fmaxf((float)cnt, 1.f);
    size_t qb = (size_t)n * 128 + h;
    outq[qb]     = q[qb]     + aq0 * inv;
    outq[qb + 1] = q[qb + 1] + aq1 * inv;
    size_t mb = (size_t)n * 384 + h;
    outmu[mb]       = mu[mb]       + am00 * inv;
    outmu[mb + 1]   = mu[mb + 1]   + am01 * inv;
    outmu[mb + 128] = mu[mb + 128] + am10 * inv;
    outmu[mb + 129] = mu[mb + 129] + am11 * inv;
    outmu[mb + 256] = mu[mb + 256] + am20 * inv;
    outmu[mb + 257] = mu[mb + 257] + am21 * inv;
}

// mcat bf16 [3N][256]: scin=[q|norm] bf16, inner f32
__global__ __launch_bounds__(256) void mix_pre(
    const bf16* __restrict__ mcat, const float* __restrict__ outq,
    bf16* __restrict__ scin, float* __restrict__ inner, int N)
{
    int i = blockIdx.x * 256 + threadIdx.x;
    if (i >= N * 128) return;
    int n = i >> 7;
    int h = i & 127;
    size_t r = (size_t)n * 768;
    float v0 = __bfloat162float(mcat[r + h]);
    float w0 = __bfloat162float(mcat[r + 128 + h]);
    float v1 = __bfloat162float(mcat[r + 256 + h]);
    float w1 = __bfloat162float(mcat[r + 384 + h]);
    float v2 = __bfloat162float(mcat[r + 512 + h]);
    float w2 = __bfloat162float(mcat[r + 640 + h]);
    float nrm = sqrtf(v0 * v0 + v1 * v1 + v2 * v2 + 1e-8f);
    inner[i] = v0 * w0 + v1 * w1 + v2 * w2;
    scin[(size_t)n * 256 + h] = __float2bfloat16(outq[i]);
    scin[(size_t)n * 256 + 128 + h] = __float2bfloat16(nrm);
}

// q += dq + dqmu*inner ; mu += mu_w * dmu_scale
__global__ __launch_bounds__(256) void mix_post(
    const bf16* __restrict__ delta, const float* __restrict__ inner,
    const bf16* __restrict__ mcat,
    float* __restrict__ outq, float* __restrict__ outmu, int N)
{
    int i = blockIdx.x * 256 + threadIdx.x;
    if (i >= N * 128) return;
    int n = i >> 7;
    int h = i & 127;
    size_t dr = (size_t)n * 384;
    float dq  = __bfloat162float(delta[dr + h]);
    float dsc = __bfloat162float(delta[dr + 128 + h]);
    float dqm = __bfloat162float(delta[dr + 256 + h]);
    outq[i] += dq + dqm * inner[i];
    size_t r = (size_t)n * 768;
    size_t mb = (size_t)n * 384 + h;
    outmu[mb]       += __bfloat162float(mcat[r + 128 + h]) * dsc;
    outmu[mb + 128] += __bfloat162float(mcat[r + 384 + h]) * dsc;
    outmu[mb + 256] += __bfloat162float(mcat[r + 640 + h]) * dsc;
}

extern "C" void kernel_launch(void* const* d_in, const int* in_sizes, int n_in,
                              void* d_out, int out_size, void* d_ws, size_t ws_size,
                              hipStream_t stream)
{
    const float* q   = (const float*)d_in[0];
    const float* mu  = (const float*)d_in[1];
    const int*   ei  = (const int*)d_in[2];
    const float* rbf = (const float*)d_in[3];
    const float* uv  = (const float*)d_in[4];
    const float* cut = (const float*)d_in[5];
    const float* Wi1 = (const float*)d_in[6];
    const float* bi1 = (const float*)d_in[7];
    const float* Wi2 = (const float*)d_in[8];
    const float* bi2 = (const float*)d_in[9];
    const float* Wf1 = (const float*)d_in[10];
    const float* bf1 = (const float*)d_in[11];
    const float* Wf2 = (const float*)d_in[12];
    const float* bf2 = (const float*)d_in[13];
    const float* Wv  = (const float*)d_in[14];
    const float* Ws1 = (const float*)d_in[15];
    const float* bs1 = (const float*)d_in[16];
    const float* Ws2 = (const float*)d_in[17];
    const float* bs2 = (const float*)d_in[18];

    const int H = 128;
    const int N = in_sizes[0] / H;     // 32768
    const int E = in_sizes[5];         // 262144
    const int NCHUNK = 8;
    const int TGT_PER = N / NCHUNK;    // 4096 targets per chunk
    const int SLOT = E / NCHUNK + 4096;// 36864 (%128==0), ~24 sigma slack
    (void)n_in; (void)out_size;

    // ---- workspace layout ----
    // Region [0, 134.4 MB): transient per-phase buffers (P1/P3 dead by P5;
    // P5's mcat..delta alias from base). Sort arrays + weights live ABOVE it.
    char* ws = (char*)d_ws;
    size_t o = 0;
    auto take = [&](size_t b) { char* p = ws + o; o += (b + 255) & ~(size_t)255; return p; };
    bf16*  xb   = (bf16*)take((size_t)N * 384 * 2);       // 25.2 MB [P1..P3]
    bf16*  mub  = (bf16*)take((size_t)N * 384 * 2);       // 25.2 MB [P3]
    bf16*  filc = (bf16*)take((size_t)SLOT * 384 * 2);    // 28.3 MB [P3]; x1 alias P1
    bf16*  hf   = (bf16*)take((size_t)SLOT * 128 * 2);    //  9.4 MB [P3]
    // P5 aliases from base: mcat 50.3 + scin 16.8 + inner 16.8 + s1 25.2 + delta 25.2
    bf16*  mcat  = (bf16*)ws;
    bf16*  scin  = mcat + (size_t)N * 768;
    float* inner = (float*)(scin + (size_t)N * 256);
    bf16*  s1    = (bf16*)(inner + (size_t)N * 128);
    bf16*  delta = s1 + (size_t)N * 384;
    const size_t P5_END = (size_t)N * (768 + 256 + 384 + 384) * 2 + (size_t)N * 128 * 4;
    if (o < P5_END) o = (P5_END + 255) & ~(size_t)255;
    // persistent (live across all phases):
    int*   perm   = (int*)take((size_t)NCHUNK * SLOT * 4);
    int*   srcp   = (int*)take((size_t)NCHUNK * SLOT * 4);
    float* cutp   = (float*)take((size_t)NCHUNK * SLOT * 4);
    float* uvp    = (float*)take((size_t)NCHUNK * SLOT * 12);
    int*   hist   = (int*)take((size_t)N * 4);
    int*   off    = (int*)take((size_t)N * 4);
    int*   cursor = (int*)take((size_t)N * 4);
    bf16*  wts    = (bf16*)take(1100000);
    if (o > ws_size) return;

    bf16* Wi1t = wts;             // [384][128]
    bf16* Wi2t = Wi1t + 49152;    // [384][384]
    bf16* Wf1t = Wi2t + 147456;   // [128][32]
    bf16* Wf2t = Wf1t + 4096;     // [384][128]
    bf16* Wvt  = Wf2t + 49152;    // [256][128]
    bf16* Ws1t = Wvt  + 32768;    // [384][256]
    bf16* Ws2t = Ws1t + 98304;    // [384][384]

    float* outq  = (float*)d_out;
    float* outmu = outq + (size_t)N * 128;

    dim3 blk(256);

    // ---- P0: weights -> bf16 transposed; mu -> bf16 ----
    {
        CvtArgs a;
        const float* wi[7] = {Wi1, Wi2, Wf1, Wf2, Wv, Ws1, Ws2};
        bf16* wo[7] = {Wi1t, Wi2t, Wf1t, Wf2t, Wvt, Ws1t, Ws2t};
        int K[7]  = {128, 384, 20, 128, 128, 256, 384};
        int Nc[7] = {384, 384, 128, 384, 256, 384, 384};
        int Kp[7] = {128, 384, 32, 128, 128, 256, 384};
        int c = 0;
        for (int s = 0; s < 7; ++s) {
            a.in[s] = wi[s]; a.out[s] = wo[s];
            a.K[s] = K[s]; a.Nc[s] = Nc[s]; a.Kp[s] = Kp[s];
            a.cum[s] = c; c += Nc[s] * Kp[s];
        }
        a.cum[7] = c;
        cvt_all<<<dim3((c + 255) / 256), blk, 0, stream>>>(a);
        cvt_bf16<<<dim3((unsigned)((size_t)N * 384 / 4 / 256)), blk, 0, stream>>>(
            (const float4*)mu, mub, (size_t)N * 384 / 4);
    }

    // ---- P1: interaction MLP (full) ----
    {
        bf16* x1 = filc;   // scratch
        mgemm<float, bf16, 1><<<dim3(N / 128, 3), blk, 0, stream>>>(
            q, Wi1t, bi1, nullptr, x1, N, 128, 384, 128, nullptr);
        mgemm<bf16, bf16, 0><<<dim3(N / 128, 3), blk, 0, stream>>>(
            x1, Wi2t, bi2, nullptr, xb, N, 384, 384, 0, nullptr);
    }

    // ---- PS: counting sort by target (8 regions with fixed slack bases) ----
    zero_k<<<dim3((N / 4 + 255) / 256), blk, 0, stream>>>((float4*)hist, N / 4);
    zero_k<<<dim3(((unsigned)((size_t)NCHUNK * SLOT / 4 + 255) / 256)), blk, 0, stream>>>(
        (float4*)perm, (size_t)NCHUNK * SLOT / 4);
    zero_k<<<dim3(((unsigned)((size_t)NCHUNK * SLOT / 4 + 255) / 256)), blk, 0, stream>>>(
        (float4*)cutp, (size_t)NCHUNK * SLOT / 4);
    hist_k<<<dim3(E / 256), blk, 0, stream>>>(ei, hist, E);
    scan_k<<<dim3(1), blk, 0, stream>>>(hist, off, cursor, N, SLOT);
    scatter_k<<<dim3(E / 256), blk, 0, stream>>>(ei, uv, cut, cursor,
                                                 perm, srcp, cutp, uvp, E);

    // ---- P3: filter GEMMs (sorted order) + segmented edge reduce, 8 chunks ----
    for (int c = 0; c < NCHUNK; ++c) {
        int base = c * SLOT;
        mgemm<float, bf16, 1><<<dim3(SLOT / 128, 1), blk, 0, stream>>>(
            rbf, Wf1t, bf1, nullptr, hf, SLOT, 32, 128, 20, perm + base);
        mgemm<bf16, bf16, 2><<<dim3(SLOT / 128, 3), blk, 0, stream>>>(
            hf, Wf2t, bf2, cutp + base, filc, SLOT, 128, 384, 0, nullptr);
        edge_seg<<<dim3(TGT_PER / 4), blk, 0, stream>>>(
            xb, filc, mub, srcp, uvp, off, hist, q, mu, outq, outmu,
            c * TGT_PER, TGT_PER, base);
    }

    // ---- P5: mixing (full) ----
    mgemm<float, bf16, 0><<<dim3(3 * N / 128, 2), blk, 0, stream>>>(
        outmu, Wvt, nullptr, nullptr, mcat, 3 * N, 128, 256, 128, nullptr);
    mix_pre<<<dim3(N * 128 / 256), blk, 0, stream>>>(mcat, outq, scin, inner, N);
    mgemm<bf16, bf16, 1><<<dim3(N / 128, 3), blk, 0, stream>>>(
        scin, Ws1t, bs1, nullptr, s1, N, 256, 384, 0, nullptr);
    mgemm<bf16, bf16, 0><<<dim3(N / 128, 3), blk, 0, stream>>>(
        s1, Ws2t, bs2, nullptr, delta, N, 384, 384, 0, nullptr);
    mix_post<<<dim3(N * 128 / 256), blk, 0, stream>>>(delta, inner, mcat,
                                                      outq, outmu, N);
}

// Round 8
// 667.181 us; speedup vs baseline: 1.1427x; 1.1427x over previous
//
#include <hip/hip_runtime.h>
#include <hip/hip_bf16.h>

typedef __hip_bfloat16 bf16;
typedef __attribute__((ext_vector_type(8))) short bf16x8;
typedef __attribute__((ext_vector_type(4))) short bf16x4v;
typedef __attribute__((ext_vector_type(4))) float f32x4;

__device__ __forceinline__ void gload_lds16(const void* g, void* l)
{
    __builtin_amdgcn_global_load_lds(
        (const __attribute__((address_space(1))) void*)g,
        (__attribute__((address_space(3))) void*)l, 16, 0, 0);
}

// ---------------------------------------------------------------------------
// MFMA bf16 GEMM: C = epi(A @ Bt^T + bias)
//   A [M][K] (bf16: global_load_lds staging; float: VALU-convert staging,
//   row stride ka, zero-pad k>=ka, optional row gather Aperm, gather index
//   masked with apmask so slack perm entries are always in-bounds).
//   Bt [N][K] bf16. C [M][N]. M,N %128==0.
// ---------------------------------------------------------------------------
template<typename TA, typename TC, int EPI>
__global__ __launch_bounds__(256) void mgemm(
    const TA* __restrict__ A, const bf16* __restrict__ Bt,
    const float* __restrict__ bias, const float* __restrict__ rowscale,
    TC* __restrict__ C, int M, int K, int N, int ka,
    const int* __restrict__ Aperm, unsigned apmask)
{
    __shared__ __align__(16) bf16 As[128 * 32];
    __shared__ __align__(16) bf16 Bs[128 * 32];
    const int tid = threadIdx.x;
    const int lane = tid & 63;
    const int wave = tid >> 6;
    const int col16 = lane & 15;
    const int quad = lane >> 4;
    const int wm = (wave & 1) * 64;
    const int wn = (wave >> 1) * 64;
    const size_t m0 = (size_t)blockIdx.x * 128;
    const int n0 = blockIdx.y * 128;

    f32x4 acc[4][4];
#pragma unroll
    for (int i = 0; i < 4; ++i)
#pragma unroll
        for (int j = 0; j < 4; ++j) acc[i][j] = (f32x4){0.f, 0.f, 0.f, 0.f};

    const int rbase = wave * 32;
    const int srow = lane >> 2;
    const int schk = lane & 3;

    for (int k0 = 0; k0 < K; k0 += 32) {
        if constexpr (sizeof(TA) == 2) {
            const bf16* g0 = (const bf16*)A + (m0 + rbase + srow) * (size_t)K + k0 + schk * 8;
            gload_lds16(g0, As + rbase * 32);
            gload_lds16(g0 + 16 * (size_t)K, As + (rbase + 16) * 32);
        } else {
#pragma unroll
            for (int r = 0; r < 4; ++r) {
                int p = tid + 256 * r;
                int row = p >> 3, kp = p & 7;
                int kg = k0 + kp * 4;
                size_t arow = Aperm ? (size_t)(unsigned)(Aperm[m0 + row] & (int)apmask)
                                    : (m0 + row);
                float4 v = make_float4(0.f, 0.f, 0.f, 0.f);
                if (kg < ka) v = *(const float4*)((const float*)A + arow * (size_t)ka + kg);
                bf16 t[4] = {__float2bfloat16(v.x), __float2bfloat16(v.y),
                             __float2bfloat16(v.z), __float2bfloat16(v.w)};
                *(bf16x4v*)(As + row * 32 + kp * 4) = *(const bf16x4v*)t;
            }
        }
        {
            const bf16* g0 = Bt + (size_t)(n0 + rbase + srow) * K + k0 + schk * 8;
            gload_lds16(g0, Bs + rbase * 32);
            gload_lds16(g0 + 16 * (size_t)K, Bs + (rbase + 16) * 32);
        }
        __syncthreads();

        bf16x8 a[4], b[4];
#pragma unroll
        for (int i = 0; i < 4; ++i)
            a[i] = *(const bf16x8*)(As + (wm + i * 16 + col16) * 32 + quad * 8);
#pragma unroll
        for (int j = 0; j < 4; ++j)
            b[j] = *(const bf16x8*)(Bs + (wn + j * 16 + col16) * 32 + quad * 8);
#pragma unroll
        for (int i = 0; i < 4; ++i)
#pragma unroll
            for (int j = 0; j < 4; ++j)
                acc[i][j] = __builtin_amdgcn_mfma_f32_16x16x32_bf16(a[i], b[j], acc[i][j], 0, 0, 0);
        __syncthreads();
    }

#pragma unroll
    for (int j = 0; j < 4; ++j) {
        int col = n0 + wn + j * 16 + col16;
        float bv = bias ? bias[col] : 0.f;
#pragma unroll
        for (int i = 0; i < 4; ++i) {
#pragma unroll
            for (int r = 0; r < 4; ++r) {
                size_t row = m0 + wm + i * 16 + quad * 4 + r;
                float v = acc[i][j][r] + bv;
                if (EPI == 1) v = v / (1.f + expf(-v));
                if (EPI == 2) v *= rowscale[row];
                if constexpr (sizeof(TC) == 2)
                    ((bf16*)C)[row * (size_t)N + col] = __float2bfloat16(v);
                else
                    ((float*)C)[row * (size_t)N + col] = v;
            }
        }
    }
}

// Fused weight transpose+convert for all 7 weights.
struct CvtArgs {
    const float* in[7];
    bf16* out[7];
    int K[7], Nc[7], Kp[7];
    int cum[8];
};
__global__ __launch_bounds__(256) void cvt_all(CvtArgs a)
{
    int i = blockIdx.x * 256 + threadIdx.x;
#pragma unroll
    for (int s = 0; s < 7; ++s) {
        if (i >= a.cum[s] && i < a.cum[s + 1]) {
            int j = i - a.cum[s];
            int n = j / a.Kp[s], k = j - n * a.Kp[s];
            a.out[s][j] = __float2bfloat16(
                k < a.K[s] ? a.in[s][(size_t)k * a.Nc[s] + n] : 0.f);
        }
    }
}

__global__ __launch_bounds__(256) void cvt_bf16(
    const float4* __restrict__ in, bf16* __restrict__ out, size_t n4)
{
    size_t i = (size_t)blockIdx.x * 256 + threadIdx.x;
    if (i >= n4) return;
    float4 v = in[i];
    bf16 t[4] = {__float2bfloat16(v.x), __float2bfloat16(v.y),
                 __float2bfloat16(v.z), __float2bfloat16(v.w)};
    *(bf16x4v*)(out + i * 4) = *(const bf16x4v*)t;
}

__global__ __launch_bounds__(256) void zero_k(float4* __restrict__ p, size_t n4)
{
    size_t i = (size_t)blockIdx.x * 256 + threadIdx.x;
    if (i < n4) p[i] = make_float4(0.f, 0.f, 0.f, 0.f);
}

// ---- counting sort by target ----
__global__ __launch_bounds__(256) void hist_k(
    const int* __restrict__ ei, int* __restrict__ hist, int E)
{
    int e = blockIdx.x * 256 + threadIdx.x;
    if (e < E) atomicAdd(&hist[ei[e]], 1);
}

// Single block, 256 threads, 128 targets each. Two regions: targets <16384
// start at 0, targets >=16384 start at SLOT1 (fixed slack base).
__global__ __launch_bounds__(256) void scan_k(
    const int* __restrict__ hist, int* __restrict__ off,
    int* __restrict__ cursor, int N, int SLOT1)
{
    __shared__ int ps[257];
    int tid = threadIdx.x;
    int base = tid * 128;
    int s = 0;
    for (int i = 0; i < 128; ++i) s += hist[base + i];
    ps[tid] = s;
    __syncthreads();
    if (tid == 0) {
        int run = 0;
        for (int i = 0; i < 256; ++i) { int t = ps[i]; ps[i] = run; run += t; }
        ps[256] = run;
    }
    __syncthreads();
    int T0 = ps[128];
    int run = ps[tid];
    for (int i = 0; i < 128; ++i) {
        int n = base + i;
        int o = (n < 16384) ? run : SLOT1 + run - T0;
        off[n] = o; cursor[n] = o;
        run += hist[n];
    }
    if (tid == 255) off[N] = SLOT1 + run - T0;
}

__global__ __launch_bounds__(256) void scatter_k(
    const int* __restrict__ ei, const float* __restrict__ uv,
    const float* __restrict__ cut, int* __restrict__ cursor,
    int* __restrict__ perm, int* __restrict__ srcp,
    float* __restrict__ cutp, float* __restrict__ uvp, int E)
{
    int e = blockIdx.x * 256 + threadIdx.x;
    if (e >= E) return;
    int tgt = ei[e];
    int pos = atomicAdd(&cursor[tgt], 1);
    perm[pos] = e;
    srcp[pos] = ei[E + e];
    cutp[pos] = cut[e];
    uvp[pos * 3 + 0] = uv[e * 3 + 0];
    uvp[pos * 3 + 1] = uv[e * 3 + 1];
    uvp[pos * 3 + 2] = uv[e * 3 + 2];
}

// ---- segmented edge reduction: one wave per target, unrolled x2 ----
// Segment length from hist (off[n+1] would cross region slack).
__global__ __launch_bounds__(256) void edge_seg(
    const bf16* __restrict__ x, const bf16* __restrict__ filt,
    const bf16* __restrict__ mub, const int* __restrict__ srcp,
    const float* __restrict__ uvp, const int* __restrict__ off,
    const int* __restrict__ hist,
    const float* __restrict__ q, const float* __restrict__ mu,
    float* __restrict__ outq, float* __restrict__ outmu,
    int t0, int tcount, int base)
{
    int t = blockIdx.x * 4 + (threadIdx.x >> 6);
    if (t >= tcount) return;
    int n = t0 + t;
    int lane = threadIdx.x & 63;
    int h = lane * 2;
    int p0 = off[n];
    int cnt = hist[n];
    int p1 = p0 + cnt;

    float aq0 = 0.f, aq1 = 0.f;
    float am00 = 0.f, am01 = 0.f, am10 = 0.f, am11 = 0.f, am20 = 0.f, am21 = 0.f;

#define EDGE_LOAD(P, S) \
    const bf16* fp##S = filt + (size_t)((P) - base) * 384; \
    int src##S = srcp[P]; \
    const bf16* xp##S = x + (size_t)src##S * 384; \
    const bf16* mp##S = mub + (size_t)src##S * 384; \
    __hip_bfloat162 fq##S = *(const __hip_bfloat162*)(fp##S + h); \
    __hip_bfloat162 fr##S = *(const __hip_bfloat162*)(fp##S + 128 + h); \
    __hip_bfloat162 fm##S = *(const __hip_bfloat162*)(fp##S + 256 + h); \
    __hip_bfloat162 xq##S = *(const __hip_bfloat162*)(xp##S + h); \
    __hip_bfloat162 xr##S = *(const __hip_bfloat162*)(xp##S + 128 + h); \
    __hip_bfloat162 xm##S = *(const __hip_bfloat162*)(xp##S + 256 + h); \
    __hip_bfloat162 m0##S = *(const __hip_bfloat162*)(mp##S + h); \
    __hip_bfloat162 m1##S = *(const __hip_bfloat162*)(mp##S + 128 + h); \
    __hip_bfloat162 m2##S = *(const __hip_bfloat162*)(mp##S + 256 + h); \
    float u0##S = uvp[(P) * 3 + 0]; \
    float u1##S = uvp[(P) * 3 + 1]; \
    float u2##S = uvp[(P) * 3 + 2];

#define EDGE_ACC(S) { \
    float xq0_ = __bfloat162float(xq##S.x) * __bfloat162float(fq##S.x); \
    float xq1_ = __bfloat162float(xq##S.y) * __bfloat162float(fq##S.y); \
    float xr0_ = __bfloat162float(xr##S.x) * __bfloat162float(fr##S.x); \
    float xr1_ = __bfloat162float(xr##S.y) * __bfloat162float(fr##S.y); \
    float xm0_ = __bfloat162float(xm##S.x) * __bfloat162float(fm##S.x); \
    float xm1_ = __bfloat162float(xm##S.y) * __bfloat162float(fm##S.y); \
    aq0 += xq0_; aq1 += xq1_; \
    am00 += fmaf(u0##S, xr0_, __bfloat162float(m0##S.x) * xm0_); \
    am01 += fmaf(u0##S, xr1_, __bfloat162float(m0##S.y) * xm1_); \
    am10 += fmaf(u1##S, xr0_, __bfloat162float(m1##S.x) * xm0_); \
    am11 += fmaf(u1##S, xr1_, __bfloat162float(m1##S.y) * xm1_); \
    am20 += fmaf(u2##S, xr0_, __bfloat162float(m2##S.x) * xm0_); \
    am21 += fmaf(u2##S, xr1_, __bfloat162float(m2##S.y) * xm1_); }

    int p = p0;
    for (; p + 2 <= p1; p += 2) {
        EDGE_LOAD(p, A)
        EDGE_LOAD(p + 1, B)
        EDGE_ACC(A)
        EDGE_ACC(B)
    }
    if (p < p1) {
        EDGE_LOAD(p, A)
        EDGE_ACC(A)
    }
#undef EDGE_LOAD
#undef EDGE_ACC

    float inv = 1.f / fmaxf((float)cnt, 1.f);
    size_t qb = (size_t)n * 128 + h;
    outq[qb]     = q[qb]     + aq0 * inv;
    outq[qb + 1] = q[qb + 1] + aq1 * inv;
    size_t mb = (size_t)n * 384 + h;
    outmu[mb]       = mu[mb]       + am00 * inv;
    outmu[mb + 1]   = mu[mb + 1]   + am01 * inv;
    outmu[mb + 128] = mu[mb + 128] + am10 * inv;
    outmu[mb + 129] = mu[mb + 129] + am11 * inv;
    outmu[mb + 256] = mu[mb + 256] + am20 * inv;
    outmu[mb + 257] = mu[mb + 257] + am21 * inv;
}

// mcat bf16 [3N][256] -> scin=[q|norm] bf16, inner f32. 2 channels/thread.
__global__ __launch_bounds__(256) void mix_pre(
    const bf16* __restrict__ mcat, const float* __restrict__ outq,
    bf16* __restrict__ scin, float* __restrict__ inner, int N)
{
    int i = blockIdx.x * 256 + threadIdx.x;
    if (i >= N * 64) return;
    int n = i >> 6;
    int h = (i & 63) * 2;
    size_t r = (size_t)n * 768;
    __hip_bfloat162 v0 = *(const __hip_bfloat162*)(mcat + r + h);
    __hip_bfloat162 w0 = *(const __hip_bfloat162*)(mcat + r + 128 + h);
    __hip_bfloat162 v1 = *(const __hip_bfloat162*)(mcat + r + 256 + h);
    __hip_bfloat162 w1 = *(const __hip_bfloat162*)(mcat + r + 384 + h);
    __hip_bfloat162 v2 = *(const __hip_bfloat162*)(mcat + r + 512 + h);
    __hip_bfloat162 w2 = *(const __hip_bfloat162*)(mcat + r + 640 + h);
    float v0x = __bfloat162float(v0.x), v0y = __bfloat162float(v0.y);
    float v1x = __bfloat162float(v1.x), v1y = __bfloat162float(v1.y);
    float v2x = __bfloat162float(v2.x), v2y = __bfloat162float(v2.y);
    float nx = sqrtf(v0x * v0x + v1x * v1x + v2x * v2x + 1e-8f);
    float ny = sqrtf(v0y * v0y + v1y * v1y + v2y * v2y + 1e-8f);
    float ix = v0x * __bfloat162float(w0.x) + v1x * __bfloat162float(w1.x)
             + v2x * __bfloat162float(w2.x);
    float iy = v0y * __bfloat162float(w0.y) + v1y * __bfloat162float(w1.y)
             + v2y * __bfloat162float(w2.y);
    *(float2*)(inner + (size_t)n * 128 + h) = make_float2(ix, iy);
    float2 qv = *(const float2*)(outq + (size_t)n * 128 + h);
    __hip_bfloat162 qb; qb.x = __float2bfloat16(qv.x); qb.y = __float2bfloat16(qv.y);
    __hip_bfloat162 nb; nb.x = __float2bfloat16(nx);  nb.y = __float2bfloat16(ny);
    *(__hip_bfloat162*)(scin + (size_t)n * 256 + h) = qb;
    *(__hip_bfloat162*)(scin + (size_t)n * 256 + 128 + h) = nb;
}

// q += dq + dqmu*inner ; mu += mu_w * dmu_scale. 2 channels/thread.
__global__ __launch_bounds__(256) void mix_post(
    const bf16* __restrict__ delta, const float* __restrict__ inner,
    const bf16* __restrict__ mcat,
    float* __restrict__ outq, float* __restrict__ outmu, int N)
{
    int i = blockIdx.x * 256 + threadIdx.x;
    if (i >= N * 64) return;
    int n = i >> 6;
    int h = (i & 63) * 2;
    size_t dr = (size_t)n * 384;
    __hip_bfloat162 dq2  = *(const __hip_bfloat162*)(delta + dr + h);
    __hip_bfloat162 ds2  = *(const __hip_bfloat162*)(delta + dr + 128 + h);
    __hip_bfloat162 dm2  = *(const __hip_bfloat162*)(delta + dr + 256 + h);
    float2 in2 = *(const float2*)(inner + (size_t)n * 128 + h);
    float2* oq = (float2*)(outq + (size_t)n * 128 + h);
    float2 qv = *oq;
    qv.x += __bfloat162float(dq2.x) + __bfloat162float(dm2.x) * in2.x;
    qv.y += __bfloat162float(dq2.y) + __bfloat162float(dm2.y) * in2.y;
    *oq = qv;
    float dsx = __bfloat162float(ds2.x), dsy = __bfloat162float(ds2.y);
    size_t r = (size_t)n * 768;
    size_t mb = (size_t)n * 384 + h;
    __hip_bfloat162 w0 = *(const __hip_bfloat162*)(mcat + r + 128 + h);
    __hip_bfloat162 w1 = *(const __hip_bfloat162*)(mcat + r + 384 + h);
    __hip_bfloat162 w2 = *(const __hip_bfloat162*)(mcat + r + 640 + h);
    float2* om0 = (float2*)(outmu + mb);
    float2* om1 = (float2*)(outmu + mb + 128);
    float2* om2 = (float2*)(outmu + mb + 256);
    float2 a0 = *om0, a1 = *om1, a2 = *om2;
    a0.x += __bfloat162float(w0.x) * dsx; a0.y += __bfloat162float(w0.y) * dsy;
    a1.x += __bfloat162float(w1.x) * dsx; a1.y += __bfloat162float(w1.y) * dsy;
    a2.x += __bfloat162float(w2.x) * dsx; a2.y += __bfloat162float(w2.y) * dsy;
    *om0 = a0; *om1 = a1; *om2 = a2;
}

extern "C" void kernel_launch(void* const* d_in, const int* in_sizes, int n_in,
                              void* d_out, int out_size, void* d_ws, size_t ws_size,
                              hipStream_t stream)
{
    const float* q   = (const float*)d_in[0];
    const float* mu  = (const float*)d_in[1];
    const int*   ei  = (const int*)d_in[2];
    const float* rbf = (const float*)d_in[3];
    const float* uv  = (const float*)d_in[4];
    const float* cut = (const float*)d_in[5];
    const float* Wi1 = (const float*)d_in[6];
    const float* bi1 = (const float*)d_in[7];
    const float* Wi2 = (const float*)d_in[8];
    const float* bi2 = (const float*)d_in[9];
    const float* Wf1 = (const float*)d_in[10];
    const float* bf1 = (const float*)d_in[11];
    const float* Wf2 = (const float*)d_in[12];
    const float* bf2 = (const float*)d_in[13];
    const float* Wv  = (const float*)d_in[14];
    const float* Ws1 = (const float*)d_in[15];
    const float* bs1 = (const float*)d_in[16];
    const float* Ws2 = (const float*)d_in[17];
    const float* bs2 = (const float*)d_in[18];

    const int H = 128;
    const int N = in_sizes[0] / H;   // 32768
    const int E = in_sizes[5];       // 262144
    const int SLOT1 = E / 2 + 4096;  // 135168, %128==0
    (void)n_in; (void)out_size;

    // ---- workspace layout (round-6 proven) ----
    char* ws = (char*)d_ws;
    size_t o = 0;
    auto take = [&](size_t b) { char* p = ws + o; o += (b + 255) & ~(size_t)255; return p; };
    bf16*  xb     = (bf16*)take((size_t)N * 384 * 2);        // 25.2 MB [P1..P3]
    bf16*  mub    = (bf16*)take((size_t)N * 384 * 2);        // 25.2 MB [P3]
    bf16*  filc   = (bf16*)take((size_t)SLOT1 * 384 * 2);    // 103.8 MB [P3]
    bf16*  hf     = (bf16*)take((size_t)SLOT1 * 128 * 2);    // 34.6 MB [P3]
    int*   perm   = (int*)take((size_t)2 * SLOT1 * 4);
    int*   srcp   = (int*)take((size_t)2 * SLOT1 * 4);
    float* cutp   = (float*)take((size_t)2 * SLOT1 * 4);
    float* uvp    = (float*)take((size_t)2 * SLOT1 * 12);
    int*   hist   = (int*)take((size_t)N * 4);
    int*   off    = (int*)take((size_t)(N + 64) * 4);
    int*   cursor = (int*)take((size_t)N * 4);
    bf16*  wts    = (bf16*)take(1100000);
    if (o > ws_size) return;
    // P5 aliases (xb/mub/filc dead): 134.3 MB < 188.8 MB transient region
    bf16*  mcat  = (bf16*)ws;
    bf16*  scin  = mcat + (size_t)N * 768;
    float* inner = (float*)(scin + (size_t)N * 256);
    bf16*  s1    = (bf16*)(inner + (size_t)N * 128);
    bf16*  delta = s1 + (size_t)N * 384;

    bf16* Wi1t = wts;             // [384][128]
    bf16* Wi2t = Wi1t + 49152;    // [384][384]
    bf16* Wf1t = Wi2t + 147456;   // [128][32]
    bf16* Wf2t = Wf1t + 4096;     // [384][128]
    bf16* Wvt  = Wf2t + 49152;    // [256][128]
    bf16* Ws1t = Wvt  + 32768;    // [384][256]
    bf16* Ws2t = Ws1t + 98304;    // [384][384]

    float* outq  = (float*)d_out;
    float* outmu = outq + (size_t)N * 128;

    dim3 blk(256);

    // ---- P0: weights -> bf16 transposed; mu -> bf16 ----
    {
        CvtArgs a;
        const float* wi[7] = {Wi1, Wi2, Wf1, Wf2, Wv, Ws1, Ws2};
        bf16* wo[7] = {Wi1t, Wi2t, Wf1t, Wf2t, Wvt, Ws1t, Ws2t};
        int K[7]  = {128, 384, 20, 128, 128, 256, 384};
        int Nc[7] = {384, 384, 128, 384, 256, 384, 384};
        int Kp[7] = {128, 384, 32, 128, 128, 256, 384};
        int c = 0;
        for (int s = 0; s < 7; ++s) {
            a.in[s] = wi[s]; a.out[s] = wo[s];
            a.K[s] = K[s]; a.Nc[s] = Nc[s]; a.Kp[s] = Kp[s];
            a.cum[s] = c; c += Nc[s] * Kp[s];
        }
        a.cum[7] = c;
        cvt_all<<<dim3((c + 255) / 256), blk, 0, stream>>>(a);
        cvt_bf16<<<dim3((unsigned)((size_t)N * 384 / 4 / 256)), blk, 0, stream>>>(
            (const float4*)mu, mub, (size_t)N * 384 / 4);
    }

    // ---- P1: interaction MLP (full) ----
    {
        bf16* x1 = filc;   // scratch
        mgemm<float, bf16, 1><<<dim3(N / 128, 3), blk, 0, stream>>>(
            q, Wi1t, bi1, nullptr, x1, N, 128, 384, 128, nullptr, 0);
        mgemm<bf16, bf16, 0><<<dim3(N / 128, 3), blk, 0, stream>>>(
            x1, Wi2t, bi2, nullptr, xb, N, 384, 384, 0, nullptr, 0);
    }

    // ---- PS: counting sort by target (only hist needs zeroing; perm slack is
    // handled by the E-1 gather mask, cutp slack feeds never-read filc rows) ----
    zero_k<<<dim3((N / 4 + 255) / 256), blk, 0, stream>>>((float4*)hist, N / 4);
    hist_k<<<dim3(E / 256), blk, 0, stream>>>(ei, hist, E);
    scan_k<<<dim3(1), blk, 0, stream>>>(hist, off, cursor, N, SLOT1);
    scatter_k<<<dim3(E / 256), blk, 0, stream>>>(ei, uv, cut, cursor,
                                                 perm, srcp, cutp, uvp, E);

    // ---- P3: filter GEMMs (sorted order) + segmented edge reduce, 2 chunks ----
    for (int c = 0; c < 2; ++c) {
        int base = c * SLOT1;
        mgemm<float, bf16, 1><<<dim3(SLOT1 / 128, 1), blk, 0, stream>>>(
            rbf, Wf1t, bf1, nullptr, hf, SLOT1, 32, 128, 20,
            perm + base, (unsigned)(E - 1));
        mgemm<bf16, bf16, 2><<<dim3(SLOT1 / 128, 3), blk, 0, stream>>>(
            hf, Wf2t, bf2, cutp + base, filc, SLOT1, 128, 384, 0, nullptr, 0);
        edge_seg<<<dim3(16384 / 4), blk, 0, stream>>>(
            xb, filc, mub, srcp, uvp, off, hist, q, mu, outq, outmu,
            c * 16384, 16384, base);
    }

    // ---- P5: mixing (full) ----
    mgemm<float, bf16, 0><<<dim3(3 * N / 128, 2), blk, 0, stream>>>(
        outmu, Wvt, nullptr, nullptr, mcat, 3 * N, 128, 256, 128, nullptr, 0);
    mix_pre<<<dim3(N * 64 / 256), blk, 0, stream>>>(mcat, outq, scin, inner, N);
    mgemm<bf16, bf16, 1><<<dim3(N / 128, 3), blk, 0, stream>>>(
        scin, Ws1t, bs1, nullptr, s1, N, 256, 384, 0, nullptr, 0);
    mgemm<bf16, bf16, 0><<<dim3(N / 128, 3), blk, 0, stream>>>(
        s1, Ws2t, bs2, nullptr, delta, N, 384, 384, 0, nullptr, 0);
    mix_post<<<dim3(N * 64 / 256), blk, 0, stream>>>(delta, inner, mcat,
                                                     outq, outmu, N);
}